// Round 6
// baseline (1250.359 us; speedup 1.0000x reference)
//
#include <hip/hip_runtime.h>

// CKAFormer R6 (from proven R5):
// - G gemm: split-K 32 (1152 blocks -> 4.5/CU residency) on a flattened 1-D
//   grid with XCD-aware z-swizzle: bid&7 = z-low (round-robin XCD heuristic),
//   so each XCD's L2 holds its 4 x 1MB k-slices of XnT.
// - Non-TRI gemms: grid transposed (blockIdx.x = n-tile, fastest) so the 8
//   column-blocks of one xm row-tile run concurrently across XCDs (LLC-hot A)
//   and each XCD keeps one Gb column slice L2-resident.
// - Everything else R5-proven: bf16 ping-pong master, TRI G, pre-swizzled
//   layouts + global_load_lds 16B staging (0 bank conflicts), fused rownorm
//   into update epilogue (ssacc) + rsqrt_k, launch_bounds(256,3).

#define N_ROWS 16384
#define DIM 1024
#define HID 16
#define OUTD 64
#define DEPTH 6
#define GAMMA 1e-4f

typedef short bf16x8 __attribute__((ext_vector_type(8)));
typedef unsigned short u16x8 __attribute__((ext_vector_type(8)));
typedef float f32x4 __attribute__((ext_vector_type(4)));

#define AS1C(p) ((const __attribute__((address_space(1))) void*)(p))
#define AS3(p)  ((__attribute__((address_space(3))) void*)(p))

__device__ __forceinline__ unsigned short f2bf(float f) {
    unsigned u = __builtin_bit_cast(unsigned, f);
    u += 0x7fffu + ((u >> 16) & 1u);   // round-to-nearest-even
    return (unsigned short)(u >> 16);
}
__device__ __forceinline__ float b2f(ushort u) {
    unsigned x = ((unsigned)u) << 16;
    return __builtin_bit_cast(float, x);
}
// stored offset of logical element n within a swizzled row keyed by (row&7)
__device__ __forceinline__ int swz(int n, int row) {
    return (n & ~63) | ((((n >> 3) & 7) ^ (row & 7)) << 3) | (n & 7);
}

// ---------------------------------------------------------------------------
// Once per launch: master Xm = bf16(X) swizzled rows + rinv[row] = 1/||X[row]||.
__global__ __launch_bounds__(256) void tobf16_k(const float* __restrict__ X,
        ushort* __restrict__ Xm, float* __restrict__ rinv) {
    int row = blockIdx.x, t = threadIdx.x;
    float4 v = ((const float4*)(X + (size_t)row * DIM))[t];
    ushort4 o4;
    o4.x = f2bf(v.x); o4.y = f2bf(v.y); o4.z = f2bf(v.z); o4.w = f2bf(v.w);
    *(ushort4*)(Xm + (size_t)row * DIM + swz(t * 4, row)) = o4;
    float ss = v.x * v.x + v.y * v.y + v.z * v.z + v.w * v.w;
    for (int o = 32; o > 0; o >>= 1) ss += __shfl_down(ss, o);
    __shared__ float wsum[4];
    if ((t & 63) == 0) wsum[t >> 6] = ss;
    __syncthreads();
    if (t == 0) rinv[row] = 1.0f / sqrtf(wsum[0] + wsum[1] + wsum[2] + wsum[3]);
}

// ---------------------------------------------------------------------------
__global__ __launch_bounds__(256) void rsqrt_k(const float* __restrict__ ssacc,
        float* __restrict__ rinv) {
    int i = blockIdx.x * 256 + threadIdx.x;
    rinv[i] = 1.0f / sqrtf(ssacc[i]);
}

// ---------------------------------------------------------------------------
// XnT[d][k] = bf16(Xm[k][d] * rinv[k]), swizzled by d. LDS 64x65 f32 tile.
__global__ __launch_bounds__(256) void transpose_k(const ushort* __restrict__ Xm,
        const float* __restrict__ rinv, ushort* __restrict__ XnT) {
    int r0 = blockIdx.x * 64;   // source row (k) tile
    int c0 = blockIdx.y * 64;   // source col (d) tile
    int t = threadIdx.x;
    __shared__ float ts[64 * 65];
    __shared__ float riS[64];
    if (t < 64) riS[t] = rinv[r0 + t];
    __syncthreads();
#pragma unroll
    for (int i = 0; i < 2; ++i) {
        int idx = i * 256 + t;
        int r = idx >> 3, lg = idx & 7;
        int rr = r0 + r;
        const ushort* p = Xm + (size_t)rr * DIM + c0 + ((lg ^ (rr & 7)) << 3);
        u16x8 a = *(const u16x8*)p;
        float s = riS[r];
        float* d = &ts[r * 65 + lg * 8];
#pragma unroll
        for (int u = 0; u < 8; ++u) d[u] = b2f(a[u]) * s;
    }
    __syncthreads();
#pragma unroll
    for (int i = 0; i < 2; ++i) {
        int g = i * 256 + t;
        int c = g >> 3;
        int rg = g & 7;
        u16x8 pk;
#pragma unroll
        for (int u = 0; u < 8; ++u) pk[u] = f2bf(ts[(rg * 8 + u) * 65 + c]);
        *(u16x8*)(XnT + (size_t)(c0 + c) * N_ROWS + r0 + ((rg ^ (c & 7)) << 3)) = pk;
    }
}

// ---------------------------------------------------------------------------
__global__ __launch_bounds__(256) void prep_w1t_k(const float* __restrict__ W1,
        ushort* __restrict__ W1T) {
    int idx = blockIdx.x * 256 + threadIdx.x;   // 16384
    int h = idx >> 10, j = idx & 1023;
    W1T[idx] = f2bf(W1[j * HID + h]);
}

// ---------------------------------------------------------------------------
// z[m][h] = rv[m] * (Xm[m]·W1[:,h]) + b1[h]   (rv=nullptr -> no scale; final).
__global__ __launch_bounds__(256) void zgemm_k(const ushort* __restrict__ Xm,
        const ushort* __restrict__ W1T, const float* __restrict__ b1,
        float* __restrict__ z, const float* __restrict__ rv) {
    int t = threadIdx.x;
    int wave = t >> 6, lane = t & 63;
    int rl = lane & 15, q = lane >> 4;
    int rowbase = blockIdx.x * 64 + wave * 16;
    int m = rowbase + rl;
    int msw = m & 7;
    const ushort* arow = Xm + (size_t)m * DIM;
    const ushort* brow = W1T + (size_t)rl * DIM + q * 8;
    f32x4 acc = {0.f, 0.f, 0.f, 0.f};
#pragma unroll 8
    for (int kt = 0; kt < DIM; kt += 32) {
        int gl = ((kt >> 3) & 7) | q;
        int off = (kt & ~63) + ((gl ^ msw) << 3);
        bf16x8 a = *(const bf16x8*)(arow + off);
        bf16x8 b = *(const bf16x8*)(brow + kt);
        acc = __builtin_amdgcn_mfma_f32_16x16x32_bf16(a, b, acc, 0, 0, 0);
    }
#pragma unroll
    for (int rg = 0; rg < 4; ++rg) {
        int mm = rowbase + q * 4 + rg;
        float s = rv ? rv[mm] : 1.0f;
        z[(size_t)mm * HID + rl] = acc[rg] * s + b1[rl];
    }
}

// ---------------------------------------------------------------------------
// Per row: h = relu(z); logits = h@W2 + b2; softmax -> Pb (swizzled by m&7)
// + PTb (rows o, swizzled by o&7), or (do_softmax=0) logits f32 to out.
__global__ __launch_bounds__(256) void head_k(const float* __restrict__ z,
        const float* __restrict__ W2, const float* __restrict__ b2,
        ushort* __restrict__ Pb, ushort* __restrict__ PTb,
        float* __restrict__ out, int do_softmax) {
    __shared__ float w2s[HID * OUTD];
    __shared__ float b2s[OUTD];
    int t = threadIdx.x;
    ((float4*)w2s)[t] = ((const float4*)W2)[t];
    if (t < OUTD) b2s[t] = b2[t];
    __syncthreads();
    int m = blockIdx.x * 256 + t;
    float h[HID];
    const float4* zp = (const float4*)(z + (size_t)m * HID);
#pragma unroll
    for (int i = 0; i < 4; ++i) {
        float4 v = zp[i];
        h[i * 4 + 0] = fmaxf(v.x, 0.f); h[i * 4 + 1] = fmaxf(v.y, 0.f);
        h[i * 4 + 2] = fmaxf(v.z, 0.f); h[i * 4 + 3] = fmaxf(v.w, 0.f);
    }
    float lo[OUTD];
#pragma unroll
    for (int o = 0; o < OUTD; ++o) lo[o] = b2s[o];
    for (int i = 0; i < HID; ++i) {
        float hv = h[i];
#pragma unroll
        for (int o = 0; o < OUTD; ++o) lo[o] += hv * w2s[i * OUTD + o];
    }
    if (do_softmax) {
        float mx = lo[0];
#pragma unroll
        for (int o = 1; o < OUTD; ++o) mx = fmaxf(mx, lo[o]);
        float sm = 0.f;
#pragma unroll
        for (int o = 0; o < OUTD; ++o) { float e = __expf(lo[o] - mx); lo[o] = e; sm += e; }
        float inv = 1.0f / sm;
#pragma unroll
        for (int o8 = 0; o8 < 8; ++o8) {
            u16x8 pk;
#pragma unroll
            for (int u = 0; u < 8; ++u) pk[u] = f2bf(lo[o8 * 8 + u] * inv);
            ((u16x8*)(Pb + (size_t)m * OUTD))[o8 ^ (m & 7)] = pk;
        }
#pragma unroll
        for (int o = 0; o < OUTD; ++o)
            PTb[(size_t)o * N_ROWS + swz(m, o)] = f2bf(lo[o] * inv);
    } else {
        float4* op = (float4*)(out + (size_t)m * OUTD);
#pragma unroll
        for (int o4 = 0; o4 < 16; ++o4) {
            float4 v; v.x = lo[o4 * 4 + 0]; v.y = lo[o4 * 4 + 1];
            v.z = lo[o4 * 4 + 2]; v.w = lo[o4 * 4 + 3];
            op[o4] = v;
        }
    }
}

// ---------------------------------------------------------------------------
// Gb[n][k] = bf16(-G[min][max]) swizzled by n; PtXTb[d][o] = bf16(PtXTf)
// swizzled by d; PtXTf elems zeroed after read (first 16384 = ssacc).
__global__ __launch_bounds__(256) void castgp_k(const float* __restrict__ Gf,
        float* __restrict__ PtXTf, ushort* __restrict__ Gb,
        ushort* __restrict__ PtXTb) {
    int idx = blockIdx.x * 256 + threadIdx.x;   // 278528 units
    if (idx < 262144) {
        int n = idx >> 8;
        int so = (idx & 255) * 4;
        int k0 = (so & ~63) | ((((so >> 3) & 7) ^ (n & 7)) << 3) | (so & 7);
        ushort4 o;
        float v0, v1, v2, v3;
        v0 = (k0 + 0 > n) ? Gf[(size_t)n * DIM + k0 + 0] : Gf[(size_t)(k0 + 0) * DIM + n];
        v1 = (k0 + 1 > n) ? Gf[(size_t)n * DIM + k0 + 1] : Gf[(size_t)(k0 + 1) * DIM + n];
        v2 = (k0 + 2 > n) ? Gf[(size_t)n * DIM + k0 + 2] : Gf[(size_t)(k0 + 2) * DIM + n];
        v3 = (k0 + 3 > n) ? Gf[(size_t)n * DIM + k0 + 3] : Gf[(size_t)(k0 + 3) * DIM + n];
        o.x = f2bf(-v0); o.y = f2bf(-v1); o.z = f2bf(-v2); o.w = f2bf(-v3);
        *(ushort4*)(Gb + (size_t)n * DIM + so) = o;
    } else {
        int vv = idx - 262144;                  // 16384 units
        int d = vv >> 4;
        int so = (vv & 15) * 4;
        int k0 = ((((so >> 3) & 7) ^ (d & 7)) << 3) | (so & 7);
        float* src = PtXTf + (size_t)d * OUTD + k0;
        float4 v = *(const float4*)src;
        ushort4 o;
        o.x = f2bf(v.x); o.y = f2bf(v.y); o.z = f2bf(v.z); o.w = f2bf(v.w);
        *(ushort4*)(PtXTb + (size_t)d * OUTD + so) = o;
        *(float4*)src = float4{0.f, 0.f, 0.f, 0.f};   // prep ssacc region
    }
}

// ---------------------------------------------------------------------------
// NT MFMA GEMM (R5-proven body). Non-TRI: blockIdx.x = n-tile (fastest,
// XCD round-robin -> A row-tile LLC-hot, B slice L2-pinned), blockIdx.y =
// m-tile, blockIdx.z = split-K. TRI: flattened 1-D grid 8*36*ZHI; bid&7 =
// z-low (-> XCD), decode tile + z-high; upper-triangle 128x128 tiles.
// EPI 0: atomicAdd f32 C. EPI 1: seg0 acc scaled by rinv[m]; epilogue writes
// bf16 master + accumulates row sum-of-squares into ssacc.
template<int BM, int BN, int EPI, int TRI>
__global__ __launch_bounds__(256, 3) void gemm_nt_k(
        const ushort* __restrict__ A0, int lda0,
        const ushort* __restrict__ B0, int ldb0, int k0len,
        const ushort* __restrict__ A1, int lda1,
        const ushort* __restrict__ B1, int ldb1, int k1len,
        float* __restrict__ C, int ldc,
        const float* __restrict__ rinv, float gamma,
        float* __restrict__ ssacc) {
    constexpr int WTN = BN / 2;
    constexpr int NF = WTN / 16;
    constexpr int NAW = BM / 64;     // waves staging A
    constexpr int NBW = BN / 64;     // waves staging B
    __shared__ ushort ls[(BM + BN) * 64];
    ushort* lsA = ls;
    ushort* lsB = ls + BM * 64;
    int t = threadIdx.x;
    int wave = t >> 6, lane = t & 63;
    int rl = lane & 15, q = lane >> 4;
    int wm = wave & 1, wn = wave >> 1;
    int m0, n0, zidx;
    if (TRI) {
        int bid = blockIdx.x;            // 8 * 36 * zhi_count
        int rest = bid >> 3;             // tile + z-high
        int bx = rest % 36, tm = 0;
        int zhi = rest / 36;
        zidx = (bid & 7) | (zhi << 3);
        while (bx >= 8 - tm) { bx -= 8 - tm; ++tm; }
        m0 = tm * 128; n0 = (tm + bx) * 128;
    } else {
        n0 = blockIdx.x * BN; m0 = blockIdx.y * BM; zidx = blockIdx.z;
    }
    int lrow8 = lane >> 3, lgrp = lane & 7;
    bool isA = wave < NAW;
    bool active = wave < NAW + NBW;
    int wlocal = isA ? wave : wave - NAW;
    ushort* dstb = ls + (isA ? 0 : BM * 64) + wlocal * 4096;

    f32x4 acc[4][NF];
#pragma unroll
    for (int i = 0; i < 4; ++i)
#pragma unroll
        for (int j = 0; j < NF; ++j) acc[i][j] = f32x4{0.f, 0.f, 0.f, 0.f};
    float rvv[4][4];

    for (int seg = 0; seg < 2; ++seg) {
        int klen = seg ? k1len : k0len;
        if (klen > 0) {
            const ushort* OPA = seg ? A1 : A0;
            const ushort* OPB = seg ? B1 : B0;
            int ldaS = seg ? lda1 : lda0;
            int ldbS = seg ? ldb1 : ldb0;
            int kb = seg ? 0 : zidx * k0len;
            const ushort* srcb;
            size_t ldS;
            if (isA) {
                srcb = OPA + (size_t)(m0 + wlocal * 64 + lrow8) * ldaS + lgrp * 8;
                ldS = (size_t)ldaS;
            } else {
                srcb = OPB + (size_t)(n0 + wlocal * 64 + lrow8) * ldbS + lgrp * 8;
                ldS = (size_t)ldbS;
            }
            srcb += kb;
            for (int kt = 0; kt < klen; kt += 64) {
                if (active) {
#pragma unroll
                    for (int c = 0; c < 8; ++c)
                        __builtin_amdgcn_global_load_lds(AS1C(srcb + c * 8 * ldS),
                                                         AS3(dstb + c * 512), 16, 0, 0);
                    srcb += 64;
                }
                __syncthreads();
#pragma unroll
                for (int s = 0; s < 2; ++s) {
                    bf16x8 af[4], bfr[NF];
#pragma unroll
                    for (int i = 0; i < 4; ++i) {
                        int row = wm * 64 + i * 16 + rl;
                        int sg = ((s << 2) | q) ^ (row & 7);
                        af[i] = *(const bf16x8*)&lsA[row * 64 + sg * 8];
                    }
#pragma unroll
                    for (int j = 0; j < NF; ++j) {
                        int row = wn * WTN + j * 16 + rl;
                        int sg = ((s << 2) | q) ^ (row & 7);
                        bfr[j] = *(const bf16x8*)&lsB[row * 64 + sg * 8];
                    }
#pragma unroll
                    for (int i = 0; i < 4; ++i)
#pragma unroll
                        for (int j = 0; j < NF; ++j)
                            acc[i][j] = __builtin_amdgcn_mfma_f32_16x16x32_bf16(
                                af[i], bfr[j], acc[i][j], 0, 0, 0);
                }
                __syncthreads();
            }
        }
        if (EPI == 1 && seg == 0) {
#pragma unroll
            for (int i = 0; i < 4; ++i)
#pragma unroll
                for (int rg = 0; rg < 4; ++rg)
                    rvv[i][rg] = rinv[m0 + wm * 64 + i * 16 + q * 4 + rg];
#pragma unroll
            for (int i = 0; i < 4; ++i)
#pragma unroll
                for (int j = 0; j < NF; ++j)
#pragma unroll
                    for (int rg = 0; rg < 4; ++rg)
                        acc[i][j][rg] *= rvv[i][rg];
        }
    }

    if (EPI == 0) {
#pragma unroll
        for (int i = 0; i < 4; ++i)
#pragma unroll
            for (int j = 0; j < NF; ++j)
#pragma unroll
                for (int rg = 0; rg < 4; ++rg) {
                    int m = m0 + wm * 64 + i * 16 + q * 4 + rg;
                    int n = n0 + wn * WTN + j * 16 + rl;
                    atomicAdd(&C[(size_t)m * ldc + n], acc[i][j][rg]);
                }
    } else {
#pragma unroll
        for (int i = 0; i < 4; ++i)
#pragma unroll
            for (int rg = 0; rg < 4; ++rg) {
                int m = m0 + wm * 64 + i * 16 + q * 4 + rg;
                float ssl = 0.f;
#pragma unroll
                for (int j = 0; j < NF; ++j) {
                    int n = n0 + wn * WTN + j * 16 + rl;
                    int so = swz(n, m);
                    float base = b2f(A0[(size_t)m * lda0 + so]);
                    float vf = base * rvv[i][rg] + gamma * acc[i][j][rg];
                    ((ushort*)C)[(size_t)m * ldc + so] = f2bf(vf);
                    ssl += vf * vf;
                }
                ssl += __shfl_xor(ssl, 1);
                ssl += __shfl_xor(ssl, 2);
                ssl += __shfl_xor(ssl, 4);
                ssl += __shfl_xor(ssl, 8);
                if (rl == 0) atomicAdd(&ssacc[m], ssl);
            }
    }
}

// ---------------------------------------------------------------------------
extern "C" void kernel_launch(void* const* d_in, const int* in_sizes, int n_in,
                              void* d_out, int out_size, void* d_ws, size_t ws_size,
                              hipStream_t stream) {
    const float* X = (const float*)d_in[0];
    const float* W1 = (const float*)d_in[1];
    const float* b1 = (const float*)d_in[2];
    const float* W2 = (const float*)d_in[3];
    const float* b2 = (const float*)d_in[4];
    float* out = (float*)d_out;
    char* ws = (char*)d_ws;

    constexpr size_t O_BufA  = 0;                                     // 33,554,432
    constexpr size_t O_BufB  = O_BufA + (size_t)N_ROWS * DIM * 2;     // 33,554,432
    constexpr size_t O_Pb    = O_BufB + (size_t)N_ROWS * DIM * 2;     //  2,097,152
    constexpr size_t O_PTb   = O_Pb + (size_t)N_ROWS * OUTD * 2;      //  2,097,152
    constexpr size_t O_Gf    = O_PTb + (size_t)OUTD * N_ROWS * 2;     //  4,194,304
    constexpr size_t O_PtXTf = O_Gf + (size_t)DIM * DIM * 4;          //    262,144
    constexpr size_t O_Gb    = O_PtXTf + (size_t)DIM * OUTD * 4;      //  2,097,152
    constexpr size_t O_PtXTb = O_Gb + (size_t)DIM * DIM * 2;          //    131,072
    constexpr size_t O_riv   = O_PtXTb + (size_t)DIM * OUTD * 2;      //     65,536
    constexpr size_t O_z     = O_riv + (size_t)N_ROWS * 4;            //  1,048,576
    constexpr size_t O_W1T   = O_z + (size_t)N_ROWS * HID * 4;        //     32,768
    // total 79,134,720 B — proven footprint

    ushort* bufA  = (ushort*)(ws + O_BufA);
    ushort* bufB  = (ushort*)(ws + O_BufB);
    ushort* Pb    = (ushort*)(ws + O_Pb);
    ushort* PTb   = (ushort*)(ws + O_PTb);
    float*  Gf    = (float*)(ws + O_Gf);
    float*  PtXTf = (float*)(ws + O_PtXTf);   // first 16384 floats double as ssacc
    ushort* Gb    = (ushort*)(ws + O_Gb);
    ushort* PtXTb = (ushort*)(ws + O_PtXTb);
    float*  riv   = (float*)(ws + O_riv);
    float*  z     = (float*)(ws + O_z);
    ushort* W1T   = (ushort*)(ws + O_W1T);
    float*  ssacc = PtXTf;
    (void)in_sizes; (void)n_in; (void)out_size; (void)ws_size;

    prep_w1t_k<<<64, 256, 0, stream>>>(W1, W1T);
    tobf16_k<<<N_ROWS, 256, 0, stream>>>(X, bufA, riv);

    ushort* xm  = bufA;   // current master X_t (bf16, swizzled rows)
    ushort* alt = bufB;   // scratch: XnT during iter, then becomes X_{t+1}

    for (int it = 0; it < DEPTH; ++it) {
        transpose_k<<<dim3(N_ROWS / 64, DIM / 64), 256, 0, stream>>>(xm, riv, alt);
        zgemm_k<<<N_ROWS / 64, 256, 0, stream>>>(xm, W1T, b1, z, riv);
        head_k<<<N_ROWS / 256, 256, 0, stream>>>(z, W2, b2, Pb, PTb, nullptr, 1);
        hipMemsetAsync(Gf, 0, (size_t)(DIM * DIM + DIM * OUTD) * sizeof(float), stream);
        // G = XnT . XnT^T : 36 upper-tri tiles x split-K 32, XCD-z-swizzled
        gemm_nt_k<128, 128, 0, 1><<<dim3(8 * 36 * 4, 1, 1), 256, 0, stream>>>(
            alt, N_ROWS, alt, N_ROWS, 512,
            nullptr, 0, nullptr, 0, 0,
            Gf, DIM, nullptr, 0.f, nullptr);
        // PtX^T[d][o] = XnT . PTb^T : split-K 64 (n-tile on x)
        gemm_nt_k<128, 64, 0, 0><<<dim3(1, 8, 64), 256, 0, stream>>>(
            alt, N_ROWS, PTb, N_ROWS, 256,
            nullptr, 0, nullptr, 0, 0,
            PtXTf, OUTD, nullptr, 0.f, nullptr);
        castgp_k<<<1088, 256, 0, stream>>>(Gf, PtXTf, Gb, PtXTb);
        // X_{t+1} = Xn + g*(P@PtX - Xn@G); writes `alt`; accumulates ssacc
        gemm_nt_k<128, 128, 1, 0><<<dim3(DIM / 128, N_ROWS / 128, 1), 256, 0, stream>>>(
            xm, DIM, Gb, DIM, 1024,
            Pb, OUTD, PtXTb, OUTD, OUTD,
            (float*)alt, DIM, riv, GAMMA, ssacc);
        rsqrt_k<<<N_ROWS / 256, 256, 0, stream>>>(ssacc, riv);
        ushort* tmp = xm; xm = alt; alt = tmp;   // ping-pong
    }

    // final: out = relu(X@W1 + b1) @ W2 + b2  (unnormalized master, rv=nullptr)
    zgemm_k<<<N_ROWS / 64, 256, 0, stream>>>(xm, W1T, b1, z, nullptr);
    head_k<<<N_ROWS / 256, 256, 0, stream>>>(z, W2, b2, Pb, PTb, out, 0);
}

// Round 7
// 1088.286 us; speedup vs baseline: 1.1489x; 1.1489x over previous
//
#include <hip/hip_runtime.h>

// CKAFormer R7 (from R5-proven structure; R6 post-mortem: G gemm is ATOMIC-bound):
// - G gemm: split-K 16 (R5 atomic count) + R6's XCD z-swizzle (FETCH 117->17MB win)
//   on flattened grid 8*36*2, bid&7 = z-low.
// - Atomic epilogue (G, PtXT): packed bf16x2 atomics (global_atomic_pk_add_bf16)
//   over adjacent-n lane pairs via shfl_xor -> 2x fewer atomic ops, 2x fewer bytes.
//   Accumulators Gacc/PtXacc are bf16; castgp negates via sign-bit XOR. Precision
//   is gamma-shielded (bf16 G accumulation error ~0.1 abs x 1e-4 -> negligible).
// - Non-TRI grids reverted to exact R5 mappings (m0 = blockIdx.x).
// - Everything else R5-proven: bf16 ping-pong master, pre-swizzled layouts +
//   global_load_lds 16B staging (0 bank conflicts), fused rownorm (ssacc+rsqrt),
//   launch_bounds(256,3).

#define N_ROWS 16384
#define DIM 1024
#define HID 16
#define OUTD 64
#define DEPTH 6
#define GAMMA 1e-4f

typedef short bf16x8 __attribute__((ext_vector_type(8)));
typedef unsigned short u16x8 __attribute__((ext_vector_type(8)));
typedef float f32x4 __attribute__((ext_vector_type(4)));

#define AS1C(p) ((const __attribute__((address_space(1))) void*)(p))
#define AS3(p)  ((__attribute__((address_space(3))) void*)(p))

__device__ __forceinline__ unsigned short f2bf(float f) {
    unsigned u = __builtin_bit_cast(unsigned, f);
    u += 0x7fffu + ((u >> 16) & 1u);   // round-to-nearest-even
    return (unsigned short)(u >> 16);
}
__device__ __forceinline__ float b2f(ushort u) {
    unsigned x = ((unsigned)u) << 16;
    return __builtin_bit_cast(float, x);
}
// stored offset of logical element n within a swizzled row keyed by (row&7)
__device__ __forceinline__ int swz(int n, int row) {
    return (n & ~63) | ((((n >> 3) & 7) ^ (row & 7)) << 3) | (n & 7);
}

// packed bf16x2 atomic add at p (4B-aligned pair)
__device__ __forceinline__ void atom_pk_bf16(ushort* p, ushort lo, ushort hi) {
#if __has_builtin(__builtin_amdgcn_global_atomic_fadd_v2bf16)
    typedef short s16x2 __attribute__((ext_vector_type(2)));
    s16x2 v;
    v[0] = (short)lo; v[1] = (short)hi;
    __builtin_amdgcn_global_atomic_fadd_v2bf16(
        (__attribute__((address_space(1))) s16x2*)p, v);
#else
    unsigned* up = (unsigned*)p;
    unsigned expected = *up;
    while (true) {
        float flo = b2f((ushort)(expected & 0xffffu)) + b2f(lo);
        float fhi = b2f((ushort)(expected >> 16)) + b2f(hi);
        unsigned desired = (unsigned)f2bf(flo) | ((unsigned)f2bf(fhi) << 16);
        unsigned old = atomicCAS(up, expected, desired);
        if (old == expected) break;
        expected = old;
    }
#endif
}

// ---------------------------------------------------------------------------
// Once per launch: master Xm = bf16(X) swizzled rows + rinv[row] = 1/||X[row]||.
__global__ __launch_bounds__(256) void tobf16_k(const float* __restrict__ X,
        ushort* __restrict__ Xm, float* __restrict__ rinv) {
    int row = blockIdx.x, t = threadIdx.x;
    float4 v = ((const float4*)(X + (size_t)row * DIM))[t];
    ushort4 o4;
    o4.x = f2bf(v.x); o4.y = f2bf(v.y); o4.z = f2bf(v.z); o4.w = f2bf(v.w);
    *(ushort4*)(Xm + (size_t)row * DIM + swz(t * 4, row)) = o4;
    float ss = v.x * v.x + v.y * v.y + v.z * v.z + v.w * v.w;
    for (int o = 32; o > 0; o >>= 1) ss += __shfl_down(ss, o);
    __shared__ float wsum[4];
    if ((t & 63) == 0) wsum[t >> 6] = ss;
    __syncthreads();
    if (t == 0) rinv[row] = 1.0f / sqrtf(wsum[0] + wsum[1] + wsum[2] + wsum[3]);
}

// ---------------------------------------------------------------------------
__global__ __launch_bounds__(256) void rsqrt_k(const float* __restrict__ ssacc,
        float* __restrict__ rinv) {
    int i = blockIdx.x * 256 + threadIdx.x;
    rinv[i] = 1.0f / sqrtf(ssacc[i]);
}

// ---------------------------------------------------------------------------
// XnT[d][k] = bf16(Xm[k][d] * rinv[k]), swizzled by d. LDS 64x65 f32 tile.
__global__ __launch_bounds__(256) void transpose_k(const ushort* __restrict__ Xm,
        const float* __restrict__ rinv, ushort* __restrict__ XnT) {
    int r0 = blockIdx.x * 64;   // source row (k) tile
    int c0 = blockIdx.y * 64;   // source col (d) tile
    int t = threadIdx.x;
    __shared__ float ts[64 * 65];
    __shared__ float riS[64];
    if (t < 64) riS[t] = rinv[r0 + t];
    __syncthreads();
#pragma unroll
    for (int i = 0; i < 2; ++i) {
        int idx = i * 256 + t;
        int r = idx >> 3, lg = idx & 7;
        int rr = r0 + r;
        const ushort* p = Xm + (size_t)rr * DIM + c0 + ((lg ^ (rr & 7)) << 3);
        u16x8 a = *(const u16x8*)p;
        float s = riS[r];
        float* d = &ts[r * 65 + lg * 8];
#pragma unroll
        for (int u = 0; u < 8; ++u) d[u] = b2f(a[u]) * s;
    }
    __syncthreads();
#pragma unroll
    for (int i = 0; i < 2; ++i) {
        int g = i * 256 + t;
        int c = g >> 3;
        int rg = g & 7;
        u16x8 pk;
#pragma unroll
        for (int u = 0; u < 8; ++u) pk[u] = f2bf(ts[(rg * 8 + u) * 65 + c]);
        *(u16x8*)(XnT + (size_t)(c0 + c) * N_ROWS + r0 + ((rg ^ (c & 7)) << 3)) = pk;
    }
}

// ---------------------------------------------------------------------------
__global__ __launch_bounds__(256) void prep_w1t_k(const float* __restrict__ W1,
        ushort* __restrict__ W1T) {
    int idx = blockIdx.x * 256 + threadIdx.x;   // 16384
    int h = idx >> 10, j = idx & 1023;
    W1T[idx] = f2bf(W1[j * HID + h]);
}

// ---------------------------------------------------------------------------
// z[m][h] = rv[m] * (Xm[m]·W1[:,h]) + b1[h]   (rv=nullptr -> no scale; final).
__global__ __launch_bounds__(256) void zgemm_k(const ushort* __restrict__ Xm,
        const ushort* __restrict__ W1T, const float* __restrict__ b1,
        float* __restrict__ z, const float* __restrict__ rv) {
    int t = threadIdx.x;
    int wave = t >> 6, lane = t & 63;
    int rl = lane & 15, q = lane >> 4;
    int rowbase = blockIdx.x * 64 + wave * 16;
    int m = rowbase + rl;
    int msw = m & 7;
    const ushort* arow = Xm + (size_t)m * DIM;
    const ushort* brow = W1T + (size_t)rl * DIM + q * 8;
    f32x4 acc = {0.f, 0.f, 0.f, 0.f};
#pragma unroll 8
    for (int kt = 0; kt < DIM; kt += 32) {
        int gl = ((kt >> 3) & 7) | q;
        int off = (kt & ~63) + ((gl ^ msw) << 3);
        bf16x8 a = *(const bf16x8*)(arow + off);
        bf16x8 b = *(const bf16x8*)(brow + kt);
        acc = __builtin_amdgcn_mfma_f32_16x16x32_bf16(a, b, acc, 0, 0, 0);
    }
#pragma unroll
    for (int rg = 0; rg < 4; ++rg) {
        int mm = rowbase + q * 4 + rg;
        float s = rv ? rv[mm] : 1.0f;
        z[(size_t)mm * HID + rl] = acc[rg] * s + b1[rl];
    }
}

// ---------------------------------------------------------------------------
// Per row: h = relu(z); logits = h@W2 + b2; softmax -> Pb (swizzled by m&7)
// + PTb (rows o, swizzled by o&7), or (do_softmax=0) logits f32 to out.
__global__ __launch_bounds__(256) void head_k(const float* __restrict__ z,
        const float* __restrict__ W2, const float* __restrict__ b2,
        ushort* __restrict__ Pb, ushort* __restrict__ PTb,
        float* __restrict__ out, int do_softmax) {
    __shared__ float w2s[HID * OUTD];
    __shared__ float b2s[OUTD];
    int t = threadIdx.x;
    ((float4*)w2s)[t] = ((const float4*)W2)[t];
    if (t < OUTD) b2s[t] = b2[t];
    __syncthreads();
    int m = blockIdx.x * 256 + t;
    float h[HID];
    const float4* zp = (const float4*)(z + (size_t)m * HID);
#pragma unroll
    for (int i = 0; i < 4; ++i) {
        float4 v = zp[i];
        h[i * 4 + 0] = fmaxf(v.x, 0.f); h[i * 4 + 1] = fmaxf(v.y, 0.f);
        h[i * 4 + 2] = fmaxf(v.z, 0.f); h[i * 4 + 3] = fmaxf(v.w, 0.f);
    }
    float lo[OUTD];
#pragma unroll
    for (int o = 0; o < OUTD; ++o) lo[o] = b2s[o];
    for (int i = 0; i < HID; ++i) {
        float hv = h[i];
#pragma unroll
        for (int o = 0; o < OUTD; ++o) lo[o] += hv * w2s[i * OUTD + o];
    }
    if (do_softmax) {
        float mx = lo[0];
#pragma unroll
        for (int o = 1; o < OUTD; ++o) mx = fmaxf(mx, lo[o]);
        float sm = 0.f;
#pragma unroll
        for (int o = 0; o < OUTD; ++o) { float e = __expf(lo[o] - mx); lo[o] = e; sm += e; }
        float inv = 1.0f / sm;
#pragma unroll
        for (int o8 = 0; o8 < 8; ++o8) {
            u16x8 pk;
#pragma unroll
            for (int u = 0; u < 8; ++u) pk[u] = f2bf(lo[o8 * 8 + u] * inv);
            ((u16x8*)(Pb + (size_t)m * OUTD))[o8 ^ (m & 7)] = pk;
        }
#pragma unroll
        for (int o = 0; o < OUTD; ++o)
            PTb[(size_t)o * N_ROWS + swz(m, o)] = f2bf(lo[o] * inv);
    } else {
        float4* op = (float4*)(out + (size_t)m * OUTD);
#pragma unroll
        for (int o4 = 0; o4 < 16; ++o4) {
            float4 v; v.x = lo[o4 * 4 + 0]; v.y = lo[o4 * 4 + 1];
            v.z = lo[o4 * 4 + 2]; v.w = lo[o4 * 4 + 3];
            op[o4] = v;
        }
    }
}

// ---------------------------------------------------------------------------
// Gacc/PtXacc are bf16. Gb[n][swz] = -Gacc[min(k,n)][max(k,n)] (sign-bit XOR);
// PtXTb[d][swz] = PtXacc[d][k].
__global__ __launch_bounds__(256) void castgp_k(const ushort* __restrict__ Gacc,
        const ushort* __restrict__ PtXacc, ushort* __restrict__ Gb,
        ushort* __restrict__ PtXTb) {
    int idx = blockIdx.x * 256 + threadIdx.x;   // 278528 units
    if (idx < 262144) {
        int n = idx >> 8;
        int so = (idx & 255) * 4;
        int k0 = (so & ~63) | ((((so >> 3) & 7) ^ (n & 7)) << 3) | (so & 7);
        ushort4 o;
        ushort v0 = (k0 + 0 > n) ? Gacc[(size_t)n * DIM + k0 + 0] : Gacc[(size_t)(k0 + 0) * DIM + n];
        ushort v1 = (k0 + 1 > n) ? Gacc[(size_t)n * DIM + k0 + 1] : Gacc[(size_t)(k0 + 1) * DIM + n];
        ushort v2 = (k0 + 2 > n) ? Gacc[(size_t)n * DIM + k0 + 2] : Gacc[(size_t)(k0 + 2) * DIM + n];
        ushort v3 = (k0 + 3 > n) ? Gacc[(size_t)n * DIM + k0 + 3] : Gacc[(size_t)(k0 + 3) * DIM + n];
        o.x = v0 ^ 0x8000u; o.y = v1 ^ 0x8000u;
        o.z = v2 ^ 0x8000u; o.w = v3 ^ 0x8000u;
        *(ushort4*)(Gb + (size_t)n * DIM + so) = o;
    } else {
        int vv = idx - 262144;                  // 16384 units
        int d = vv >> 4;
        int so = (vv & 15) * 4;
        int k0 = ((((so >> 3) & 7) ^ (d & 7)) << 3) | (so & 7);
        const ushort* src = PtXacc + (size_t)d * OUTD + k0;
        ushort4 o;
        o.x = src[0]; o.y = src[1]; o.z = src[2]; o.w = src[3];
        *(ushort4*)(PtXTb + (size_t)d * OUTD + so) = o;
    }
}

// ---------------------------------------------------------------------------
// NT MFMA GEMM (R5-proven body). Non-TRI: m0 = blockIdx.x*BM (R5 mapping),
// n0 = blockIdx.y*BN, zidx = blockIdx.z. TRI: flattened grid 8*36*2; bid&7 =
// z-low (XCD round-robin), zhi = (bid>>3)/36; upper-triangle 128x128 tiles.
// EPI 0: packed bf16x2 atomics into ushort C (adjacent-n lane pairs).
// EPI 1: seg0 acc scaled by rinv[m]; epilogue writes bf16 master + row
// sum-of-squares into ssacc.
template<int BM, int BN, int EPI, int TRI>
__global__ __launch_bounds__(256, 3) void gemm_nt_k(
        const ushort* __restrict__ A0, int lda0,
        const ushort* __restrict__ B0, int ldb0, int k0len,
        const ushort* __restrict__ A1, int lda1,
        const ushort* __restrict__ B1, int ldb1, int k1len,
        float* __restrict__ C, int ldc,
        const float* __restrict__ rinv, float gamma,
        float* __restrict__ ssacc) {
    constexpr int WTN = BN / 2;
    constexpr int NF = WTN / 16;
    constexpr int NAW = BM / 64;     // waves staging A
    constexpr int NBW = BN / 64;     // waves staging B
    __shared__ ushort ls[(BM + BN) * 64];
    ushort* lsA = ls;
    ushort* lsB = ls + BM * 64;
    int t = threadIdx.x;
    int wave = t >> 6, lane = t & 63;
    int rl = lane & 15, q = lane >> 4;
    int wm = wave & 1, wn = wave >> 1;
    int m0, n0, zidx;
    if (TRI) {
        int bid = blockIdx.x;            // 8 * 36 * 2
        int rest = bid >> 3;
        int bx = rest % 36, tm = 0;
        int zhi = rest / 36;
        zidx = (bid & 7) | (zhi << 3);
        while (bx >= 8 - tm) { bx -= 8 - tm; ++tm; }
        m0 = tm * 128; n0 = (tm + bx) * 128;
    } else {
        m0 = blockIdx.x * BM; n0 = blockIdx.y * BN; zidx = blockIdx.z;
    }
    int lrow8 = lane >> 3, lgrp = lane & 7;
    bool isA = wave < NAW;
    bool active = wave < NAW + NBW;
    int wlocal = isA ? wave : wave - NAW;
    ushort* dstb = ls + (isA ? 0 : BM * 64) + wlocal * 4096;

    f32x4 acc[4][NF];
#pragma unroll
    for (int i = 0; i < 4; ++i)
#pragma unroll
        for (int j = 0; j < NF; ++j) acc[i][j] = f32x4{0.f, 0.f, 0.f, 0.f};
    float rvv[4][4];

    for (int seg = 0; seg < 2; ++seg) {
        int klen = seg ? k1len : k0len;
        if (klen > 0) {
            const ushort* OPA = seg ? A1 : A0;
            const ushort* OPB = seg ? B1 : B0;
            int ldaS = seg ? lda1 : lda0;
            int ldbS = seg ? ldb1 : ldb0;
            int kb = seg ? 0 : zidx * k0len;
            const ushort* srcb;
            size_t ldS;
            if (isA) {
                srcb = OPA + (size_t)(m0 + wlocal * 64 + lrow8) * ldaS + lgrp * 8;
                ldS = (size_t)ldaS;
            } else {
                srcb = OPB + (size_t)(n0 + wlocal * 64 + lrow8) * ldbS + lgrp * 8;
                ldS = (size_t)ldbS;
            }
            srcb += kb;
            for (int kt = 0; kt < klen; kt += 64) {
                if (active) {
#pragma unroll
                    for (int c = 0; c < 8; ++c)
                        __builtin_amdgcn_global_load_lds(AS1C(srcb + c * 8 * ldS),
                                                         AS3(dstb + c * 512), 16, 0, 0);
                    srcb += 64;
                }
                __syncthreads();
#pragma unroll
                for (int s = 0; s < 2; ++s) {
                    bf16x8 af[4], bfr[NF];
#pragma unroll
                    for (int i = 0; i < 4; ++i) {
                        int row = wm * 64 + i * 16 + rl;
                        int sg = ((s << 2) | q) ^ (row & 7);
                        af[i] = *(const bf16x8*)&lsA[row * 64 + sg * 8];
                    }
#pragma unroll
                    for (int j = 0; j < NF; ++j) {
                        int row = wn * WTN + j * 16 + rl;
                        int sg = ((s << 2) | q) ^ (row & 7);
                        bfr[j] = *(const bf16x8*)&lsB[row * 64 + sg * 8];
                    }
#pragma unroll
                    for (int i = 0; i < 4; ++i)
#pragma unroll
                        for (int j = 0; j < NF; ++j)
                            acc[i][j] = __builtin_amdgcn_mfma_f32_16x16x32_bf16(
                                af[i], bfr[j], acc[i][j], 0, 0, 0);
                }
                __syncthreads();
            }
        }
        if (EPI == 1 && seg == 0) {
#pragma unroll
            for (int i = 0; i < 4; ++i)
#pragma unroll
                for (int rg = 0; rg < 4; ++rg)
                    rvv[i][rg] = rinv[m0 + wm * 64 + i * 16 + q * 4 + rg];
#pragma unroll
            for (int i = 0; i < 4; ++i)
#pragma unroll
                for (int j = 0; j < NF; ++j)
#pragma unroll
                    for (int rg = 0; rg < 4; ++rg)
                        acc[i][j][rg] *= rvv[i][rg];
        }
    }

    if (EPI == 0) {
        ushort* Cb = (ushort*)C;
#pragma unroll
        for (int i = 0; i < 4; ++i)
#pragma unroll
            for (int j = 0; j < NF; ++j)
#pragma unroll
                for (int rg = 0; rg < 4; ++rg) {
                    int m = m0 + wm * 64 + i * 16 + q * 4 + rg;
                    int n = n0 + wn * WTN + j * 16 + rl;
                    float v = acc[i][j][rg];
                    float vp = __shfl_xor(v, 1);   // partner lane's (n^1) value
                    if ((rl & 1) == 0)
                        atom_pk_bf16(&Cb[(size_t)m * ldc + n], f2bf(v), f2bf(vp));
                }
    } else {
#pragma unroll
        for (int i = 0; i < 4; ++i)
#pragma unroll
            for (int rg = 0; rg < 4; ++rg) {
                int m = m0 + wm * 64 + i * 16 + q * 4 + rg;
                float ssl = 0.f;
#pragma unroll
                for (int j = 0; j < NF; ++j) {
                    int n = n0 + wn * WTN + j * 16 + rl;
                    int so = swz(n, m);
                    float base = b2f(A0[(size_t)m * lda0 + so]);
                    float vf = base * rvv[i][rg] + gamma * acc[i][j][rg];
                    ((ushort*)C)[(size_t)m * ldc + so] = f2bf(vf);
                    ssl += vf * vf;
                }
                ssl += __shfl_xor(ssl, 1);
                ssl += __shfl_xor(ssl, 2);
                ssl += __shfl_xor(ssl, 4);
                ssl += __shfl_xor(ssl, 8);
                if (rl == 0) atomicAdd(&ssacc[m], ssl);
            }
    }
}

// ---------------------------------------------------------------------------
extern "C" void kernel_launch(void* const* d_in, const int* in_sizes, int n_in,
                              void* d_out, int out_size, void* d_ws, size_t ws_size,
                              hipStream_t stream) {
    const float* X = (const float*)d_in[0];
    const float* W1 = (const float*)d_in[1];
    const float* b1 = (const float*)d_in[2];
    const float* W2 = (const float*)d_in[3];
    const float* b2 = (const float*)d_in[4];
    float* out = (float*)d_out;
    char* ws = (char*)d_ws;

    constexpr size_t O_BufA  = 0;                                     // 33,554,432
    constexpr size_t O_BufB  = O_BufA + (size_t)N_ROWS * DIM * 2;     // 33,554,432
    constexpr size_t O_Pb    = O_BufB + (size_t)N_ROWS * DIM * 2;     //  2,097,152
    constexpr size_t O_PTb   = O_Pb + (size_t)N_ROWS * OUTD * 2;      //  2,097,152
    constexpr size_t O_Gacc  = O_PTb + (size_t)OUTD * N_ROWS * 2;     //  2,097,152 bf16
    constexpr size_t O_PXacc = O_Gacc + (size_t)DIM * DIM * 2;        //    131,072 bf16
    constexpr size_t O_ssacc = O_PXacc + (size_t)DIM * OUTD * 2;      //     65,536 f32
    constexpr size_t O_Gb    = O_ssacc + (size_t)N_ROWS * 4;          //  2,097,152
    constexpr size_t O_PtXTb = O_Gb + (size_t)DIM * DIM * 2;          //    131,072
    constexpr size_t O_riv   = O_PtXTb + (size_t)DIM * OUTD * 2;      //     65,536
    constexpr size_t O_z     = O_riv + (size_t)N_ROWS * 4;            //  1,048,576
    constexpr size_t O_W1T   = O_z + (size_t)N_ROWS * HID * 4;        //     32,768
    // total 76,972,032 B — under the proven 79.1 MB footprint

    ushort* bufA  = (ushort*)(ws + O_BufA);
    ushort* bufB  = (ushort*)(ws + O_BufB);
    ushort* Pb    = (ushort*)(ws + O_Pb);
    ushort* PTb   = (ushort*)(ws + O_PTb);
    ushort* Gacc  = (ushort*)(ws + O_Gacc);
    ushort* PXacc = (ushort*)(ws + O_PXacc);
    float*  ssacc = (float*)(ws + O_ssacc);
    ushort* Gb    = (ushort*)(ws + O_Gb);
    ushort* PtXTb = (ushort*)(ws + O_PtXTb);
    float*  riv   = (float*)(ws + O_riv);
    float*  z     = (float*)(ws + O_z);
    ushort* W1T   = (ushort*)(ws + O_W1T);
    (void)in_sizes; (void)n_in; (void)out_size; (void)ws_size;

    prep_w1t_k<<<64, 256, 0, stream>>>(W1, W1T);
    tobf16_k<<<N_ROWS, 256, 0, stream>>>(X, bufA, riv);

    ushort* xm  = bufA;   // current master X_t (bf16, swizzled rows)
    ushort* alt = bufB;   // scratch: XnT during iter, then becomes X_{t+1}

    for (int it = 0; it < DEPTH; ++it) {
        transpose_k<<<dim3(N_ROWS / 64, DIM / 64), 256, 0, stream>>>(xm, riv, alt);
        zgemm_k<<<N_ROWS / 64, 256, 0, stream>>>(xm, W1T, b1, z, riv);
        head_k<<<N_ROWS / 256, 256, 0, stream>>>(z, W2, b2, Pb, PTb, nullptr, 1);
        // zero Gacc + PXacc + ssacc in one contiguous memset
        hipMemsetAsync(ws + O_Gacc, 0,
                       (size_t)DIM * DIM * 2 + (size_t)DIM * OUTD * 2
                       + (size_t)N_ROWS * 4, stream);
        // G = XnT . XnT^T : 36 upper-tri tiles x split-K 16, XCD z-swizzled
        gemm_nt_k<128, 128, 0, 1><<<dim3(8 * 36 * 2, 1, 1), 256, 0, stream>>>(
            alt, N_ROWS, alt, N_ROWS, 1024,
            nullptr, 0, nullptr, 0, 0,
            (float*)Gacc, DIM, nullptr, 0.f, nullptr);
        // PtX^T[d][o] = XnT . PTb^T : split-K 64 (R5 mapping: m-tile on x)
        gemm_nt_k<128, 64, 0, 0><<<dim3(8, 1, 64), 256, 0, stream>>>(
            alt, N_ROWS, PTb, N_ROWS, 256,
            nullptr, 0, nullptr, 0, 0,
            (float*)PXacc, OUTD, nullptr, 0.f, nullptr);
        castgp_k<<<1088, 256, 0, stream>>>(Gacc, PXacc, Gb, PtXTb);
        // X_{t+1} = Xn + g*(P@PtX - Xn@G); writes `alt`; accumulates ssacc
        gemm_nt_k<128, 128, 1, 0><<<dim3(N_ROWS / 128, DIM / 128, 1), 256, 0, stream>>>(
            xm, DIM, Gb, DIM, 1024,
            Pb, OUTD, PtXTb, OUTD, OUTD,
            (float*)alt, DIM, riv, GAMMA, ssacc);
        rsqrt_k<<<N_ROWS / 256, 256, 0, stream>>>(ssacc, riv);
        ushort* tmp = xm; xm = alt; alt = tmp;   // ping-pong
    }

    // final: out = relu(X@W1 + b1) @ W2 + b2  (unnormalized master, rv=nullptr)
    zgemm_k<<<N_ROWS / 64, 256, 0, stream>>>(xm, W1T, b1, z, nullptr);
    head_k<<<N_ROWS / 256, 256, 0, stream>>>(z, W2, b2, Pb, PTb, out, 0);
}